// Round 13
// baseline (127.775 us; speedup 1.0000x reference)
//
#include <hip/hip_runtime.h>
#include <stdint.h>

#define C_    19
#define NB    15
#define CB    (C_ * NB)          // 285 cells
#define HW    (512 * 1024)
#define NPIX  (4 * HW)           // 2097152
#define TPB   256                // 4 waves
#define WTILE 64                 // pixels per wave-tile (1 px/lane)
#define ROWS  20                 // 19 logit rows + 1 label row
#define NT    8                  // tiles per wave
#define GBLK  (NPIX / (WTILE * NT * 4))   // 1024 blocks
#define REPS  4                  // LDS replicas for bin>=2 atomics
#define KCOP  8                  // global histogram copies

// R10 structure (best measured: 57.6 us) + fused last-block finalization
// (saves ece_final launch + gap). Wave-private DMA double-buffer, zero
// main-loop barriers, merged-cell (cell += conf - (c==label)),
// bins 0/1 in registers, bin>=2 via replicated LDS atomics.
__global__ __launch_bounds__(TPB, 3)
void ece_hist(const float* __restrict__ logits,
              const int*   __restrict__ labels,
              float*       __restrict__ ws,
              float*       __restrict__ out) {
    __shared__ uint32_t tile[4][2][ROWS][WTILE];  // 40960 B (per-wave dbuf)
    __shared__ float    hist[REPS * CB];          //  4560 B

    const int tid  = threadIdx.x;
    const int wave = tid >> 6;
    const int lane = tid & 63;

    for (int i = tid; i < REPS * CB; i += TPB) hist[i] = 0.f;
    __syncthreads();                              // hist zeroed before any atomics

    float* myh = hist + (tid & (REPS - 1)) * CB;

    float d0[C_], d1[C_];                         // merged accumulators, bins 0/1
#pragma unroll
    for (int c = 0; c < C_; ++c) { d0[c] = 0.f; d1[c] = 0.f; }

    // Stage this wave's tile t into its buffer bb: 20 width-4 DMA rows.
    auto STAGE = [&](int t, int bb) {
        const int n0 = ((blockIdx.x * 4 + wave) * NT + t) * WTILE;
        const int b  = n0 >> 19;                  // HW = 2^19; tiles never straddle
        const int hw = n0 & (HW - 1);
#pragma unroll
        for (int r = 0; r < ROWS; ++r) {
            const uint32_t* src = (r < C_)
                ? (const uint32_t*)(logits + ((size_t)b * C_ + r) * HW + hw) + lane
                : (const uint32_t*)(labels + n0) + lane;
            __builtin_amdgcn_global_load_lds(
                (const __attribute__((address_space(1))) void*)src,
                (__attribute__((address_space(3))) void*)&tile[wave][bb][r][0],
                4, 0, 0);                         // lane i -> base + 4i
        }
    };

    STAGE(0, 0);
    for (int t = 0; t < NT; ++t) {
        const int cur = t & 1;
        if (t + 1 < NT) {
            STAGE(t + 1, cur ^ 1);
            asm volatile("s_waitcnt vmcnt(20)" ::: "memory");  // tile t landed
        } else {
            asm volatile("s_waitcnt vmcnt(0)" ::: "memory");
        }
        __builtin_amdgcn_sched_barrier(0);        // keep ds_reads below the wait

        float x[C_];
#pragma unroll
        for (int c = 0; c < C_; ++c) x[c] = __uint_as_float(tile[wave][cur][c][lane]);
        const int l = (int)tile[wave][cur][C_][lane];

#pragma unroll
        for (int c = 0; c < C_; ++c) x[c] = __expf(x[c]);

        // pairwise-tree sum: a[0]=x0..7, a[4]=x8..15, a[8]=x16..18
        float a[10];
#pragma unroll
        for (int j = 0; j < 9; ++j) a[j] = x[2 * j] + x[2 * j + 1];
        a[9] = x[18];
        a[0] += a[1]; a[2] += a[3]; a[4] += a[5]; a[6] += a[7]; a[8] += a[9];
        a[0] += a[2]; a[4] += a[6];
        const float inv = 1.f / (a[0] + a[4] + a[8]);

#pragma unroll
        for (int c = 0; c < C_; ++c) {
            const float conf = x[c] * inv;
            int bin = (int)ceilf(conf * (float)NB) - 1;      // reference binning
            bin = bin < 0 ? 0 : (bin > NB - 1 ? NB - 1 : bin);
            const float val = conf - ((c == l) ? 1.f : 0.f);
            d0[c] += (bin == 0) ? val : 0.f;
            d1[c] += (bin == 1) ? val : 0.f;
            if (bin >= 2) atomicAdd(&myh[c * NB + bin], val);  // ~1.5/pixel
        }
    }

    // Flush: 3-step xor-shuffle (8-lane groups) -> leader ds-atomics into replicas.
#pragma unroll
    for (int c = 0; c < C_; ++c) {
        float v0 = d0[c], v1 = d1[c];
        v0 += __shfl_xor(v0, 1); v1 += __shfl_xor(v1, 1);
        v0 += __shfl_xor(v0, 2); v1 += __shfl_xor(v1, 2);
        v0 += __shfl_xor(v0, 4); v1 += __shfl_xor(v1, 4);
        if ((tid & 7) == 0) {
            const int r = (tid >> 3) & (REPS - 1);
            atomicAdd(&hist[r * CB + c * NB + 0], v0);
            atomicAdd(&hist[r * CB + c * NB + 1], v1);
        }
    }
    __syncthreads();

    // Fold replicas -> one global atomic per cell into one of KCOP copies.
    float* wsb = ws + (size_t)(blockIdx.x & (KCOP - 1)) * CB;
    for (int i = tid; i < CB; i += TPB) {
        float s = 0.f;
#pragma unroll
        for (int r = 0; r < REPS; ++r) s += hist[r * CB + i];
        atomicAdd(&wsb[i], s);
    }

    // ---- fused finalization: last block folds KCOP copies -> scalar ----
    __shared__ bool amLast;
    __threadfence();                               // flushes visible device-wide
    if (tid == 0) {
        uint32_t prev = atomicAdd((uint32_t*)(ws + KCOP * CB), 1u);
        amLast = (prev == GBLK - 1);
    }
    __syncthreads();
    if (!amLast) return;
    __threadfence();                               // acquire: see all flushes

    float val = 0.f;
    for (int i = tid; i < CB; i += TPB) {          // 285 cells over 256 threads
        float s = 0.f;
#pragma unroll
        for (int k = 0; k < KCOP; ++k)
            s += __hip_atomic_load(&ws[k * CB + i], __ATOMIC_RELAXED,
                                   __HIP_MEMORY_SCOPE_AGENT);
        val += fabsf(s);
    }
#pragma unroll
    for (int off = 32; off; off >>= 1) val += __shfl_down(val, off);
    __shared__ float sm[4];
    if (lane == 0) sm[wave] = val;
    __syncthreads();
    if (tid == 0)
        out[0] = (sm[0] + sm[1] + sm[2] + sm[3]) / ((float)NPIX * (float)C_);
}

extern "C" void kernel_launch(void* const* d_in, const int* in_sizes, int n_in,
                              void* d_out, int out_size, void* d_ws, size_t ws_size,
                              hipStream_t stream) {
    const float* logits = (const float*)d_in[0];
    const int*   labels = (const int*)d_in[1];
    float* out = (float*)d_out;
    float* ws  = (float*)d_ws;

    // zero KCOP histogram copies + the completion counter
    hipMemsetAsync(ws, 0, ((size_t)KCOP * CB + 1) * sizeof(float), stream);
    ece_hist<<<GBLK, TPB, 0, stream>>>(logits, labels, ws, out);
}

// Round 14
// 60.576 us; speedup vs baseline: 2.1093x; 2.1093x over previous
//
#include <hip/hip_runtime.h>
#include <stdint.h>

#define C_    19
#define NB    15
#define CB    (C_ * NB)          // 285 cells
#define HW    (512 * 1024)
#define NPIX  (4 * HW)           // 2097152
#define TPB   256                // 4 waves
#define WTILE 64                 // pixels per wave-tile (1 px/lane)
#define ROWS  20                 // 19 logit rows + 1 label row
#define NT    8                  // tiles per wave
#define GBLK  (NPIX / (WTILE * NT * 4))   // 1024 blocks
#define REPS  2                  // LDS replicas for rare tt>3 atomics
#define KCOP  8                  // global histogram copies

// R10 wave-private DMA structure + cumulative register rows D0/D1/D2
// (tt<=1/2/3, R11-validated telescoping) -> LDS atomic rate 1.5 -> ~0.5/px.
// Rare tt>3 -> replicated LDS hist (NEVER global per-pixel, R11 lesson).
// Merged-cell: cell += conf - (c==label); final = sum |cell| / (N*C).
__global__ __launch_bounds__(TPB, 3)
void ece_hist(const float* __restrict__ logits,
              const int*   __restrict__ labels,
              float*       __restrict__ ws) {
    __shared__ uint32_t tile[4][2][ROWS][WTILE];  // 40960 B (per-wave dbuf)
    __shared__ float    hist[REPS * CB];          //  2280 B -> total 43240 B

    const int tid  = threadIdx.x;
    const int wave = tid >> 6;
    const int lane = tid & 63;

    for (int i = tid; i < REPS * CB; i += TPB) hist[i] = 0.f;
    __syncthreads();                              // hist zeroed before any atomics

    float* myh = hist + (tid & (REPS - 1)) * CB;

    float D0[C_], D1[C_], D2[C_];                 // cumulative rows: tt<=1, <=2, <=3
#pragma unroll
    for (int c = 0; c < C_; ++c) { D0[c] = 0.f; D1[c] = 0.f; D2[c] = 0.f; }

    // Stage this wave's tile t into its buffer bb: 20 width-4 DMA rows.
    auto STAGE = [&](int t, int bb) {
        const int n0 = ((blockIdx.x * 4 + wave) * NT + t) * WTILE;
        const int b  = n0 >> 19;                  // HW = 2^19; tiles never straddle
        const int hw = n0 & (HW - 1);
#pragma unroll
        for (int r = 0; r < ROWS; ++r) {
            const uint32_t* src = (r < C_)
                ? (const uint32_t*)(logits + ((size_t)b * C_ + r) * HW + hw) + lane
                : (const uint32_t*)(labels + n0) + lane;
            __builtin_amdgcn_global_load_lds(
                (const __attribute__((address_space(1))) void*)src,
                (__attribute__((address_space(3))) void*)&tile[wave][bb][r][0],
                4, 0, 0);                         // lane i -> base + 4i
        }
    };

    STAGE(0, 0);
    for (int t = 0; t < NT; ++t) {
        const int cur = t & 1;
        if (t + 1 < NT) {
            STAGE(t + 1, cur ^ 1);
            asm volatile("s_waitcnt vmcnt(20)" ::: "memory");  // tile t landed
        } else {
            asm volatile("s_waitcnt vmcnt(0)" ::: "memory");
        }
        __builtin_amdgcn_sched_barrier(0);        // keep ds_reads below the wait

        float x[C_];
#pragma unroll
        for (int c = 0; c < C_; ++c) x[c] = __uint_as_float(tile[wave][cur][c][lane]);
        const int l = (int)tile[wave][cur][C_][lane];

#pragma unroll
        for (int c = 0; c < C_; ++c) x[c] = __expf(x[c]);

        // pairwise-tree sum: a[0]=x0..7, a[4]=x8..15, a[8]=x16..18
        float a[10];
#pragma unroll
        for (int j = 0; j < 9; ++j) a[j] = x[2 * j] + x[2 * j + 1];
        a[9] = x[18];
        a[0] += a[1]; a[2] += a[3]; a[4] += a[5]; a[6] += a[7]; a[8] += a[9];
        a[0] += a[2]; a[4] += a[6];
        const float inv = 1.f / (a[0] + a[4] + a[8]);

#pragma unroll
        for (int c = 0; c < C_; ++c) {
            const float conf = x[c] * inv;
            const float tt   = conf * 15.f;       // ref bin = ceil(tt)-1 clamped
            const float val  = conf - ((c == l) ? 1.f : 0.f);
            D0[c] += (tt <= 1.f) ? val : 0.f;
            D1[c] += (tt <= 2.f) ? val : 0.f;
            D2[c] += (tt <= 3.f) ? val : 0.f;
            if (tt > 3.f) {                       // ~0.5/px -> replicated LDS hist
                int bin = (int)ceilf(tt) - 1;
                bin = bin > NB - 1 ? NB - 1 : bin;
                atomicAdd(&myh[c * NB + bin], val);
            }
        }
    }

    // Flush: 3-step xor-shuffle (8-lane groups) -> leader ds-atomics.
    // Telescoping: bin0 = r0, bin1 = r1 - r0, bin2 = r2 - r1.
#pragma unroll
    for (int c = 0; c < C_; ++c) {
        float r0 = D0[c], r1 = D1[c], r2 = D2[c];
        r0 += __shfl_xor(r0, 1); r1 += __shfl_xor(r1, 1); r2 += __shfl_xor(r2, 1);
        r0 += __shfl_xor(r0, 2); r1 += __shfl_xor(r1, 2); r2 += __shfl_xor(r2, 2);
        r0 += __shfl_xor(r0, 4); r1 += __shfl_xor(r1, 4); r2 += __shfl_xor(r2, 4);
        if ((tid & 7) == 0) {
            const int r = (tid >> 3) & (REPS - 1);
            atomicAdd(&hist[r * CB + c * NB + 0], r0);
            atomicAdd(&hist[r * CB + c * NB + 1], r1 - r0);
            atomicAdd(&hist[r * CB + c * NB + 2], r2 - r1);
        }
    }
    __syncthreads();

    // Fold replicas -> one global atomic per cell into one of KCOP copies.
    float* wsb = ws + (size_t)(blockIdx.x & (KCOP - 1)) * CB;
    for (int i = tid; i < CB; i += TPB) {
        float s = 0.f;
#pragma unroll
        for (int r = 0; r < REPS; ++r) s += hist[r * CB + i];
        atomicAdd(&wsb[i], s);
    }
}

// Fold KCOP copies: sce = sum_cells |cell| / (N * C)
__global__ void ece_final(const float* __restrict__ ws, float* __restrict__ out) {
    const int t = threadIdx.x;  // 320 threads = 5 waves
    float val = 0.f;
    if (t < CB) {
        float s = 0.f;
#pragma unroll
        for (int k = 0; k < KCOP; ++k) s += ws[k * CB + t];
        val = fabsf(s);
    }
#pragma unroll
    for (int off = 32; off; off >>= 1) val += __shfl_down(val, off);
    __shared__ float sm[5];
    if ((t & 63) == 0) sm[t >> 6] = val;
    __syncthreads();
    if (t == 0) {
        float tot = sm[0] + sm[1] + sm[2] + sm[3] + sm[4];
        out[0] = tot / ((float)NPIX * (float)C_);
    }
}

extern "C" void kernel_launch(void* const* d_in, const int* in_sizes, int n_in,
                              void* d_out, int out_size, void* d_ws, size_t ws_size,
                              hipStream_t stream) {
    const float* logits = (const float*)d_in[0];
    const int*   labels = (const int*)d_in[1];
    float* out = (float*)d_out;
    float* ws  = (float*)d_ws;

    hipMemsetAsync(ws, 0, (size_t)KCOP * CB * sizeof(float), stream);
    ece_hist<<<GBLK, TPB, 0, stream>>>(logits, labels, ws);
    ece_final<<<1, 320, 0, stream>>>(ws, out);
}

// Round 15
// 55.949 us; speedup vs baseline: 2.2838x; 1.0827x over previous
//
#include <hip/hip_runtime.h>
#include <stdint.h>

#define C_    19
#define NB    15
#define CB    (C_ * NB)          // 285 cells
#define HW    (512 * 1024)
#define NPIX  (4 * HW)           // 2097152
#define TPB   256                // 4 waves
#define WTILE 64                 // pixels per wave-tile (1 px/lane)
#define ROWS  20                 // 19 logit rows + 1 label row
#define NT    8                  // tiles per wave
#define GBLK  (NPIX / (WTILE * NT * 4))   // 1024 blocks
#define REPS  4                  // LDS replicas for bin>=2 atomics
#define KCOP  8                  // global histogram copies

// R10 wave-private DMA structure with WIDTH-16 staging: one global_load_lds
// covers 4 rows (lane -> row 4j+(lane>>4), col (lane&15)*16B; per-lane src
// gather, linear LDS dest). 5 VMEM instrs/tile instead of 20 -> probes the
// VMEM-instruction-queue hypothesis. Compute path byte-identical to R10.
__global__ __launch_bounds__(TPB, 3)
void ece_hist(const float* __restrict__ logits,
              const int*   __restrict__ labels,
              float*       __restrict__ ws) {
    __shared__ uint32_t tile[4][2][ROWS][WTILE];  // 40960 B (per-wave dbuf)
    __shared__ float    hist[REPS * CB];          //  4560 B

    const int tid  = threadIdx.x;
    const int wave = tid >> 6;
    const int lane = tid & 63;

    for (int i = tid; i < REPS * CB; i += TPB) hist[i] = 0.f;
    __syncthreads();                              // hist zeroed before any atomics

    float* myh = hist + (tid & (REPS - 1)) * CB;

    float d0[C_], d1[C_];                         // merged accumulators, bins 0/1
#pragma unroll
    for (int c = 0; c < C_; ++c) { d0[c] = 0.f; d1[c] = 0.f; }

    const int col  = lane & 15;                   // 16-B chunk within a row
    const int rsub = lane >> 4;                   // which of the 4 rows

    // Stage this wave's tile t into buffer bb: 5 width-16 DMA instrs cover
    // rows 0..19 (row 19 = labels, per-lane pointer select).
    auto STAGE = [&](int t, int bb) {
        const int n0 = ((blockIdx.x * 4 + wave) * NT + t) * WTILE;
        const int b  = n0 >> 19;                  // HW = 2^19; tiles never straddle
        const int hw = n0 & (HW - 1);
#pragma unroll
        for (int j = 0; j < 5; ++j) {
            const int r = 4 * j + rsub;
            const uint32_t* srcA =
                (const uint32_t*)(logits + ((size_t)b * C_ + r) * HW + hw) + col * 4;
            const uint32_t* srcB = (const uint32_t*)(labels + n0) + col * 4;
            const uint32_t* src  = (r < C_) ? srcA : srcB;   // only j==4 mixes
            __builtin_amdgcn_global_load_lds(
                (const __attribute__((address_space(1))) void*)src,
                (__attribute__((address_space(3))) void*)&tile[wave][bb][4 * j][0],
                16, 0, 0);                        // lane i -> base + 16i (rows 4j..4j+3)
        }
    };

    STAGE(0, 0);
    for (int t = 0; t < NT; ++t) {
        const int cur = t & 1;
        if (t + 1 < NT) {
            STAGE(t + 1, cur ^ 1);
            asm volatile("s_waitcnt vmcnt(5)" ::: "memory");  // tile t landed; t+1 flying
        } else {
            asm volatile("s_waitcnt vmcnt(0)" ::: "memory");
        }
        __builtin_amdgcn_sched_barrier(0);        // keep ds_reads below the wait

        float x[C_];
#pragma unroll
        for (int c = 0; c < C_; ++c) x[c] = __uint_as_float(tile[wave][cur][c][lane]);
        const int l = (int)tile[wave][cur][C_][lane];

#pragma unroll
        for (int c = 0; c < C_; ++c) x[c] = __expf(x[c]);

        // pairwise-tree sum: a[0]=x0..7, a[4]=x8..15, a[8]=x16..18
        float a[10];
#pragma unroll
        for (int j = 0; j < 9; ++j) a[j] = x[2 * j] + x[2 * j + 1];
        a[9] = x[18];
        a[0] += a[1]; a[2] += a[3]; a[4] += a[5]; a[6] += a[7]; a[8] += a[9];
        a[0] += a[2]; a[4] += a[6];
        const float inv = 1.f / (a[0] + a[4] + a[8]);

#pragma unroll
        for (int c = 0; c < C_; ++c) {
            const float conf = x[c] * inv;
            int bin = (int)ceilf(conf * (float)NB) - 1;      // reference binning
            bin = bin < 0 ? 0 : (bin > NB - 1 ? NB - 1 : bin);
            const float val = conf - ((c == l) ? 1.f : 0.f);
            d0[c] += (bin == 0) ? val : 0.f;
            d1[c] += (bin == 1) ? val : 0.f;
            if (bin >= 2) atomicAdd(&myh[c * NB + bin], val);  // ~1.5/pixel
        }
        // no barrier: buffers are wave-private
    }

    // Flush: 3-step xor-shuffle (8-lane groups) -> leader ds-atomics into replicas.
#pragma unroll
    for (int c = 0; c < C_; ++c) {
        float v0 = d0[c], v1 = d1[c];
        v0 += __shfl_xor(v0, 1); v1 += __shfl_xor(v1, 1);
        v0 += __shfl_xor(v0, 2); v1 += __shfl_xor(v1, 2);
        v0 += __shfl_xor(v0, 4); v1 += __shfl_xor(v1, 4);
        if ((tid & 7) == 0) {
            const int r = (tid >> 3) & (REPS - 1);
            atomicAdd(&hist[r * CB + c * NB + 0], v0);
            atomicAdd(&hist[r * CB + c * NB + 1], v1);
        }
    }
    __syncthreads();

    // Fold replicas -> one global atomic per cell into one of KCOP copies.
    float* wsb = ws + (size_t)(blockIdx.x & (KCOP - 1)) * CB;
    for (int i = tid; i < CB; i += TPB) {
        float s = 0.f;
#pragma unroll
        for (int r = 0; r < REPS; ++r) s += hist[r * CB + i];
        atomicAdd(&wsb[i], s);
    }
}

// Fold KCOP copies: sce = sum_cells |cell| / (N * C)
__global__ void ece_final(const float* __restrict__ ws, float* __restrict__ out) {
    const int t = threadIdx.x;  // 320 threads = 5 waves
    float val = 0.f;
    if (t < CB) {
        float s = 0.f;
#pragma unroll
        for (int k = 0; k < KCOP; ++k) s += ws[k * CB + t];
        val = fabsf(s);
    }
#pragma unroll
    for (int off = 32; off; off >>= 1) val += __shfl_down(val, off);
    __shared__ float sm[5];
    if ((t & 63) == 0) sm[t >> 6] = val;
    __syncthreads();
    if (t == 0) {
        float tot = sm[0] + sm[1] + sm[2] + sm[3] + sm[4];
        out[0] = tot / ((float)NPIX * (float)C_);
    }
}

extern "C" void kernel_launch(void* const* d_in, const int* in_sizes, int n_in,
                              void* d_out, int out_size, void* d_ws, size_t ws_size,
                              hipStream_t stream) {
    const float* logits = (const float*)d_in[0];
    const int*   labels = (const int*)d_in[1];
    float* out = (float*)d_out;
    float* ws  = (float*)d_ws;

    hipMemsetAsync(ws, 0, (size_t)KCOP * CB * sizeof(float), stream);
    ece_hist<<<GBLK, TPB, 0, stream>>>(logits, labels, ws);
    ece_final<<<1, 320, 0, stream>>>(ws, out);
}